// Round 9
// baseline (694.468 us; speedup 1.0000x reference)
//
#include <hip/hip_runtime.h>
#include <stdint.h>

// ---------------------------------------------------------------------------
// IAM_47794396069954: dual-stream axial (row-wise) cross attention + double
// 3x3 conv heads, b=2, c=64, h=w=320.  All heavy math on bf16 MFMA
// (mfma_f32_16x16x32_bf16), fp32 accumulate.  5 kernels:
//   kpack  : weights -> bf16, conv weights repacked [tap][o][c]
//   kproj  : u/d -> bf16 NCHW copy + [b,h,w,c] transpose + 4x 1x1 proj (MFMA)
//   kattn  : per-(b,h,dir,qtile) row attention, K staged in LDS
//            v6: V ALSO staged in LDS (aliases dead K buffer; exactly 40960B)
//            with T14 async-split (V global loads issued pre-QK, ds_write
//            post-QK) and (vc+c)%40 rotation to kill the c-stride bank
//            conflict.  PV no longer does 16-segment NCHW gathers.
//   kconv1 : LDS-staged implicit-GEMM 3x3 (concat 128ch) + ReLU -> mid bf16
//   kconv2 : LDS-staged implicit-GEMM 3x3 (64ch) -> fp32 NCHW, same pipeline
// NOTE (R2 lesson): __launch_bounds__(256,4) caused accumulator spills.
// NOTE (R5 lesson): t5 siblings must be CONCURRENT and co-XCD for L2 reuse.
// NOTE (R7 lesson): 16-segment channel-plane gathers feeding MFMA are the
// expensive pattern; LDS staging is an MLP converter, not just a cache.
// NOTE (R8 lesson): kattn is INVARIANT to resident-wave count (3/4/8 blocks
// all ~200us) -> per-wave serial chain bound; shorten the chain.
// MFMA 16x16x32 layouts:
//   A[m][k]: m=lane&15, k=(lane>>4)*8+j ;  B[k][n]: n=lane&15, k=(lane>>4)*8+j
//   C/D    : col=lane&15, row=(lane>>4)*4+reg
// ---------------------------------------------------------------------------

typedef __bf16 bf16;
typedef __bf16 bf16x8 __attribute__((ext_vector_type(8)));
typedef float  f32x4  __attribute__((ext_vector_type(4)));

#define MFMA(a, b, c) __builtin_amdgcn_mfma_f32_16x16x32_bf16((a), (b), (c), 0, 0, 0)

static constexpr int    HWc  = 320 * 320;      // 102400
static constexpr int    CHW  = 64 * HWc;       // 6553600
static constexpr size_t NE   = 2ull * CHW;     // 13107200 elements per tensor

// workspace layout (bf16 elements)
static constexpr size_t OFF_UBF  = 0;          // u bf16 NCHW (attn V)
static constexpr size_t OFF_DBF  = NE;         // d bf16 NCHW (attn V)
static constexpr size_t OFF_UT   = 2 * NE;     // u  [b,h,w,c]
static constexpr size_t OFF_DT   = 3 * NE;     // d  [b,h,w,c]
static constexpr size_t OFF_QUD  = 4 * NE;     // u1 [b,h,w,c]; later mid_u
static constexpr size_t OFF_KUD  = 5 * NE;     // d2
static constexpr size_t OFF_QDU  = 6 * NE;     // d1 ; later mid_d
static constexpr size_t OFF_KDU  = 7 * NE;     // u2
static constexpr size_t OFF_BUFD = 8 * NE;     // buffer_d [b,h,w,c]
static constexpr size_t OFF_BUFU = 9 * NE;     // buffer_u [b,h,w,c]
static constexpr size_t OFF_W1A  = 10 * NE;            // [9][64][128]
static constexpr size_t OFF_W2A  = OFF_W1A + 9*64*128;
static constexpr size_t OFF_W1B  = OFF_W2A + 9*64*128; // [9][64][64]
static constexpr size_t OFF_W2B  = OFF_W1B + 9*64*64;
static constexpr size_t OFF_WU1  = OFF_W2B + 9*64*64;  // [64][64]
static constexpr size_t OFF_WU2  = OFF_WU1 + 4096;
static constexpr size_t OFF_WD1  = OFF_WU2 + 4096;
static constexpr size_t OFF_WD2  = OFF_WD1 + 4096;

// ---------------------------------------------------------------------------
__global__ __launch_bounds__(256) void kpack(
    const float* __restrict__ Wu1, const float* __restrict__ Wu2,
    const float* __restrict__ Wd1, const float* __restrict__ Wd2,
    const float* __restrict__ W1a, const float* __restrict__ W1b,
    const float* __restrict__ W2a, const float* __restrict__ W2b,
    bf16* __restrict__ ws) {
  const int t = blockIdx.x * 256 + threadIdx.x;
  if (t < 9 * 64 * 128) {                 // [tap][o][c] <- W[o][c][ky][kx]
    const int c = t & 127, o = (t >> 7) & 63, tap = t >> 13;
    const int src = (o * 128 + c) * 9 + tap;
    ws[OFF_W1A + t] = (bf16)W1a[src];
    ws[OFF_W2A + t] = (bf16)W2a[src];
  }
  if (t < 9 * 64 * 64) {
    const int c = t & 63, o = (t >> 6) & 63, tap = t >> 12;
    const int src = (o * 64 + c) * 9 + tap;
    ws[OFF_W1B + t] = (bf16)W1b[src];
    ws[OFF_W2B + t] = (bf16)W2b[src];
  }
  if (t < 4096) {
    ws[OFF_WU1 + t] = (bf16)Wu1[t];
    ws[OFF_WU2 + t] = (bf16)Wu2[t];
    ws[OFF_WD1 + t] = (bf16)Wd1[t];
    ws[OFF_WD2 + t] = (bf16)Wd2[t];
  }
}

// ---------------------------------------------------------------------------
// grid (5, 640, 2): x = 64-px tile, y = b*320+h, z = stream (0=u,1=d)
__global__ __launch_bounds__(256) void kproj(const float* __restrict__ u,
                                             const float* __restrict__ d,
                                             bf16* __restrict__ ws) {
  __shared__ float ut[64][68];        // [x][c]
  __shared__ float stg[4][16][68];    // per-wave transpose stage
  const int s   = blockIdx.z;
  const int by  = blockIdx.y;               // b*320 + y
  const int b   = by / 320;
  const int y   = by % 320;
  const int x0  = blockIdx.x * 64;
  const int tid = threadIdx.x;
  const int lane = tid & 63, wv = tid >> 6;
  const int l15 = lane & 15, q4 = lane >> 4;

  const float* src = s ? d : u;
  const bf16* Wq = ws + (s ? OFF_WD1 : OFF_WU1);   // u1 / d1
  const bf16* Wk = ws + (s ? OFF_WD2 : OFF_WU2);   // u2 / d2
  bf16* xbf = ws + (s ? OFF_DBF : OFF_UBF);
  bf16* xt  = ws + (s ? OFF_DT  : OFF_UT);
  bf16* qo  = ws + (s ? OFF_QDU : OFF_QUD);        // u1->q_ud, d1->q_du
  bf16* ko  = ws + (s ? OFF_KUD : OFF_KDU);        // u2->k_du, d2->k_ud

  // phase 1: coalesced load, bf16 NCHW copy, LDS transpose stage
  {
    const int xl = lane;
    const int cb = wv * 16;
#pragma unroll
    for (int i = 0; i < 16; ++i) {
      const int c = cb + i;
      const size_t g = (size_t)(b * 64 + c) * HWc + (size_t)y * 320 + x0 + xl;
      const float v = src[g];
      xbf[g] = (bf16)v;
      ut[xl][c] = v;
    }
  }
  __syncthreads();

  // phase 1b: [b,h,w,c] transpose store
  {
    const int xl = tid >> 2;
    const int cc = (tid & 3) * 16;
    bf16x8 v0, v1;
#pragma unroll
    for (int j = 0; j < 8; ++j) {
      v0[j] = (bf16)ut[xl][cc + j];
      v1[j] = (bf16)ut[xl][cc + 8 + j];
    }
    bf16* p = xt + ((size_t)by * 320 + x0 + xl) * 64 + cc;
    *(bf16x8*)p = v0;
    *(bf16x8*)(p + 8) = v1;
  }

  // phase 2: 1x1 projections.  wave wv handles x-subtile wv*16..+15
  bf16x8 a[2];
#pragma unroll
  for (int ks = 0; ks < 2; ++ks) {
    const int xl = wv * 16 + l15;
    const int c0 = ks * 32 + q4 * 8;
#pragma unroll
    for (int j = 0; j < 8; ++j) a[ks][j] = (bf16)ut[xl][c0 + j];
  }
  const f32x4 zero4 = {0.f, 0.f, 0.f, 0.f};
  f32x4 acc[8];
#pragma unroll
  for (int i = 0; i < 8; ++i) acc[i] = zero4;
#pragma unroll
  for (int ks = 0; ks < 2; ++ks) {
#pragma unroll
    for (int ot = 0; ot < 8; ++ot) {
      const bf16* Wm = (ot < 4) ? Wq : Wk;
      const int o = (ot & 3) * 16 + l15;
      const bf16x8 bw = *(const bf16x8*)(Wm + o * 64 + ks * 32 + q4 * 8);
      acc[ot] = MFMA(a[ks], bw, acc[ot]);
    }
  }
  // epilogue: two passes (q then k), per-wave LDS transpose, 32B stores
#pragma unroll
  for (int pass = 0; pass < 2; ++pass) {
    bf16* dst = pass ? ko : qo;
#pragma unroll
    for (int ot = 0; ot < 4; ++ot)
#pragma unroll
      for (int r = 0; r < 4; ++r)
        stg[wv][q4 * 4 + r][ot * 16 + l15] = acc[pass * 4 + ot][r];
    bf16x8 v0, v1;
    const int cc = q4 * 16;
#pragma unroll
    for (int j = 0; j < 8; ++j) {
      v0[j] = (bf16)stg[wv][l15][cc + j];
      v1[j] = (bf16)stg[wv][l15][cc + 8 + j];
    }
    bf16* p = dst + ((size_t)by * 320 + x0 + wv * 16 + l15) * 64 + cc;
    *(bf16x8*)p = v0;
    *(bf16x8*)(p + 8) = v1;
  }
}

// ---------------------------------------------------------------------------
// kattn v6: 1-D grid 6400.  g -> chunk=g/40, t5=(g%40)>>3, bhdir=chunk*8+
// (g%40&7) -> t5-siblings co-XCD and concurrent (R6: FETCH 281->77MB).
// Phase 1: stage K (XOR swizzle) + ISSUE V global loads into regs.
// Phase 2: QK MFMA from LDS + register softmax (V loads in flight).
// Phase 3: barrier, ds_write V into dead K buffer ([c][v] with (vc+c)%40
//          rotation -> <=2-way banks), barrier.
// Phase 4: PV from LDS (no gathers), pch per-wave transpose, epilogue.
__global__ __launch_bounds__(256) void kattn(bf16* __restrict__ ws) {
  __shared__ __attribute__((aligned(16))) bf16 shm[20480];          // 40960 B
  __shared__ __attribute__((aligned(16))) bf16 pch[4][16][72];      //  9216 B
  const int g     = blockIdx.x;
  const int chunk = g / 40;
  const int within = g % 40;
  const int t5    = within >> 3;
  const int bhdir = chunk * 8 + (within & 7);
  const int bh    = bhdir % 640;
  const int dir   = bhdir / 640;
  const int tid = threadIdx.x;
  const int lane = tid & 63, wv = tid >> 6;
  const int l15 = lane & 15, q4 = lane >> 4;

  const bf16* Q = ws + (dir ? OFF_QDU : OFF_QUD) + (size_t)bh * 320 * 64;
  const bf16* K = ws + (dir ? OFF_KDU : OFF_KUD) + (size_t)bh * 320 * 64;
  const bf16* V = ws + (dir ? OFF_UBF : OFF_DBF) + (size_t)(bh / 320) * CHW
                + (size_t)(bh % 320) * 320;
  bf16* O = ws + (dir ? OFF_BUFU : OFF_BUFD) + (size_t)bh * 320 * 64;

  // phase 1a: stage K -> LDS (layout [t][s][r], XOR swizzle)
  for (int i = tid; i < 2560; i += 256) {
    const int px = i >> 3, s = i & 7;          // key px, c-chunk
    const int t = px >> 4, r = px & 15;
    const int off = t * 1024 + s * 128 + (((r & 7) ^ s) << 3) + ((r & 8) << 3);
    *(bf16x8*)(shm + off) = *(const bf16x8*)(K + (size_t)px * 64 + s * 8);
  }
  // phase 1b: issue V loads (coalesced, 10 per thread) - consumed in phase 3
  bf16x8 vv[10];
#pragma unroll
  for (int it = 0; it < 10; ++it) {
    const int i = tid + it * 256;
    const int c = i / 40, vc = i % 40;
    vv[it] = *(const bf16x8*)(V + (size_t)c * HWc + vc * 8);
  }
  __syncthreads();

  const f32x4 zero4 = {0.f, 0.f, 0.f, 0.f};
  const int wq0 = (t5 * 4 + wv) * 16;
  const bf16x8 a0 = *(const bf16x8*)(Q + (size_t)(wq0 + l15) * 64 + q4 * 8);
  const bf16x8 a1 = *(const bf16x8*)(Q + (size_t)(wq0 + l15) * 64 + 32 + q4 * 8);
  // swizzled read offsets (constant per lane across kt)
  const int rb0 = q4 * 128 + (((l15 & 7) ^ q4) << 3) + ((l15 & 8) << 3);
  const int rb1 = (q4 + 4) * 128 + (((l15 & 7) ^ (q4 + 4)) << 3) + ((l15 & 8) << 3);
  f32x4 sacc[20];
#pragma unroll
  for (int kt = 0; kt < 20; ++kt) sacc[kt] = zero4;
#pragma unroll
  for (int kt = 0; kt < 20; ++kt) {
    const bf16x8 b0 = *(const bf16x8*)(shm + kt * 1024 + rb0);
    const bf16x8 b1 = *(const bf16x8*)(shm + kt * 1024 + rb1);
    sacc[kt] = MFMA(a0, b0, sacc[kt]);
    sacc[kt] = MFMA(a1, b1, sacc[kt]);
  }
  // exact softmax over the 320-wide row; row wq = q4*4+r lives in this quad
  float mx[4] = {-3.0e38f, -3.0e38f, -3.0e38f, -3.0e38f};
#pragma unroll
  for (int kt = 0; kt < 20; ++kt)
#pragma unroll
    for (int r = 0; r < 4; ++r) mx[r] = fmaxf(mx[r], sacc[kt][r]);
#pragma unroll
  for (int off = 1; off < 16; off <<= 1)
#pragma unroll
    for (int r = 0; r < 4; ++r) mx[r] = fmaxf(mx[r], __shfl_xor(mx[r], off));
  float sm[4] = {0.f, 0.f, 0.f, 0.f};
#pragma unroll
  for (int kt = 0; kt < 20; ++kt)
#pragma unroll
    for (int r = 0; r < 4; ++r) {
      const float e = __expf(sacc[kt][r] - mx[r]);
      sacc[kt][r] = e;
      sm[r] += e;
    }
#pragma unroll
  for (int off = 1; off < 16; off <<= 1)
#pragma unroll
    for (int r = 0; r < 4; ++r) sm[r] += __shfl_xor(sm[r], off);
  float inv[4];
#pragma unroll
  for (int r = 0; r < 4; ++r) inv[r] = 1.f / sm[r];

  // phase 3: K dead -> write V into shm.  Layout: [c][v] rotated,
  // elem off = c*320 + ((vc + c) % 40)*8 + (v&7).  Barriers guard reuse.
  __syncthreads();
#pragma unroll
  for (int it = 0; it < 10; ++it) {
    const int i = tid + it * 256;
    const int c = i / 40, vc = i % 40;
    const int rot = (vc + c) % 40;
    *(bf16x8*)(shm + c * 320 + rot * 8) = vv[it];
  }
  __syncthreads();

  // phase 4: PV from LDS.  P goes C-layout -> pch (per-wave) -> A-layout.
  f32x4 oac[4];
#pragma unroll
  for (int ct = 0; ct < 4; ++ct) oac[ct] = zero4;
#pragma unroll
  for (int ch = 0; ch < 5; ++ch) {
#pragma unroll
    for (int j = 0; j < 4; ++j) {
      const int kt = ch * 4 + j;
#pragma unroll
      for (int r = 0; r < 4; ++r)
        pch[wv][q4 * 4 + r][j * 16 + l15] = (bf16)(sacc[kt][r] * inv[r]);
    }
    const bf16x8 p0 = *(const bf16x8*)&pch[wv][l15][q4 * 8];
    const bf16x8 p1 = *(const bf16x8*)&pch[wv][l15][32 + q4 * 8];
#pragma unroll
    for (int ct = 0; ct < 4; ++ct) {
      const int c = ct * 16 + l15;
      const int vc0 = ch * 8 + q4;           // v = ch*64 + q4*8
      const int r0 = (vc0 + c) % 40;
      const int r1 = (vc0 + 4 + c) % 40;     // +32 elements
      const bf16x8 v0 = *(const bf16x8*)(shm + c * 320 + r0 * 8);
      const bf16x8 v1 = *(const bf16x8*)(shm + c * 320 + r1 * 8);
      oac[ct] = MFMA(p0, v0, oac[ct]);
      oac[ct] = MFMA(p1, v1, oac[ct]);
    }
  }
  // epilogue: O[wq][c] -> [b,h,w,c] bf16 via per-wave LDS transpose (pch reuse)
#pragma unroll
  for (int ct = 0; ct < 4; ++ct)
#pragma unroll
    for (int r = 0; r < 4; ++r)
      pch[wv][q4 * 4 + r][ct * 16 + l15] = (bf16)oac[ct][r];
  __builtin_amdgcn_s_waitcnt(0);           // lgkm drain before re-read
  bf16x8 w0, w1;
  const int cc = q4 * 16;
#pragma unroll
  for (int j = 0; j < 8; ++j) {
    w0[j] = pch[wv][l15][cc + j];
    w1[j] = pch[wv][l15][cc + 8 + j];
  }
  bf16* p = O + (size_t)(wq0 + l15) * 64 + cc;
  *(bf16x8*)p = w0;
  *(bf16x8*)(p + 8) = w1;
}

// ---------------------------------------------------------------------------
// reg-staged slab fill: issue independent global loads first, then LDS writes.
// 2720 16B-chunks = 10 full rounds of 256 threads + 160-thread tail.
#define STAGE_SLAB(XT)                                                        \
  do {                                                                        \
    bf16x8 vr[11];                                                            \
    _Pragma("unroll") for (int it = 0; it < 10; ++it) {                       \
      const int i = tid + it * 256;                                           \
      const int row = i / 272, rem = i % 272;                                 \
      const int px = rem >> 3, chunk = rem & 7;                               \
      const int yy = y0 - 1 + row, xx = x0 - 1 + px;                          \
      bf16x8 v;                                                               \
      _Pragma("unroll") for (int j = 0; j < 8; ++j) v[j] = (bf16)0.f;         \
      if ((unsigned)yy < 320u && (unsigned)xx < 320u)                         \
        v = *(const bf16x8*)((XT) + ((size_t)yy * 320 + xx) * 64 + chunk * 8);\
      vr[it] = v;                                                             \
    }                                                                         \
    if (tid < 160) {                                                          \
      const int i = tid + 2560;                                               \
      const int row = i / 272, rem = i % 272;                                 \
      const int px = rem >> 3, chunk = rem & 7;                               \
      const int yy = y0 - 1 + row, xx = x0 - 1 + px;                          \
      bf16x8 v;                                                               \
      _Pragma("unroll") for (int j = 0; j < 8; ++j) v[j] = (bf16)0.f;         \
      if ((unsigned)yy < 320u && (unsigned)xx < 320u)                         \
        v = *(const bf16x8*)((XT) + ((size_t)yy * 320 + xx) * 64 + chunk * 8);\
      vr[10] = v;                                                             \
    }                                                                         \
    _Pragma("unroll") for (int it = 0; it < 10; ++it) {                       \
      const int i = tid + it * 256;                                           \
      const int row = i / 272, rem = i % 272;                                 \
      const int px = rem >> 3, chunk = rem & 7;                               \
      *(bf16x8*)(xs + (((row * 8 + chunk) * 34 + px) * 8)) = vr[it];          \
    }                                                                         \
    if (tid < 160) {                                                          \
      const int i = tid + 2560;                                               \
      const int row = i / 272, rem = i % 272;                                 \
      const int px = rem >> 3, chunk = rem & 7;                               \
      *(bf16x8*)(xs + (((row * 8 + chunk) * 34 + px) * 8)) = vr[10];          \
    }                                                                         \
  } while (0)

// group g = tap*2 + ks; weight fragments (4x16B, L2) for kconv1 (cin stride 128)
#define LOADW1(g, slot)                                                       \
  do {                                                                        \
    const bf16* wp_ = Wg + (size_t)((g) >> 1) * 8192 + (size_t)l15 * 128      \
                      + t * 64 + ((g) & 1) * 32 + q4 * 8;                     \
    bw[slot][0] = *(const bf16x8*)(wp_);                                      \
    bw[slot][1] = *(const bf16x8*)(wp_ + 2048);                               \
    bw[slot][2] = *(const bf16x8*)(wp_ + 4096);                               \
    bw[slot][3] = *(const bf16x8*)(wp_ + 6144);                               \
  } while (0)

// weight fragments for kconv2 (cin stride 64)
#define LOADW2(g, slot)                                                       \
  do {                                                                        \
    const bf16* wp_ = Wg + (size_t)((g) >> 1) * 4096 + (size_t)l15 * 64       \
                      + ((g) & 1) * 32 + q4 * 8;                              \
    bw[slot][0] = *(const bf16x8*)(wp_);                                      \
    bw[slot][1] = *(const bf16x8*)(wp_ + 1024);                               \
    bw[slot][2] = *(const bf16x8*)(wp_ + 2048);                               \
    bw[slot][3] = *(const bf16x8*)(wp_ + 3072);                               \
  } while (0)

// A fragments from LDS slab (4x ds_read_b128); [r][xt]
#define LOADA(g, slot)                                                        \
  do {                                                                        \
    const int ky_ = (g) / 6, kx_ = ((g) >> 1) % 3, ks_ = (g) & 1;             \
    const bf16* ap_ = xs + (((wv * 2 + ky_) * 8 + ks_ * 4 + q4) * 34          \
                            + l15 + kx_) * 8;                                 \
    af[slot][0][0] = *(const bf16x8*)(ap_);                                   \
    af[slot][0][1] = *(const bf16x8*)(ap_ + 128);                             \
    af[slot][1][0] = *(const bf16x8*)(ap_ + 2176);                            \
    af[slot][1][1] = *(const bf16x8*)(ap_ + 2304);                            \
  } while (0)

// ---------------------------------------------------------------------------
// kconv1 v4: grid (10, 40, 4): 32-px x-tile, 8-row y-tile, z = s*2+b.
// 2 phases (concat halves), slab [10 rows][8 ch-chunks][34 px] (43.5 KB).
// Inner loop: 18 tap-groups, software-pipelined (prefetch g+1 while MFMA g).
__global__ __launch_bounds__(256, 3) void kconv1(bf16* __restrict__ ws) {
  __shared__ __attribute__((aligned(16))) bf16 xs[10 * 8 * 34 * 8];  // 43520 B
  __shared__ __attribute__((aligned(16))) bf16 stg[4][16][72];       //  9216 B
  const int s = blockIdx.z >> 1, b = blockIdx.z & 1;
  const int x0 = blockIdx.x * 32;
  const int y0 = blockIdx.y * 8;
  const int tid = threadIdx.x;
  const int lane = tid & 63, wv = tid >> 6;
  const int l15 = lane & 15, q4 = lane >> 4;

  const bf16* X1 = ws + (s ? OFF_DT : OFF_UT) + (size_t)b * CHW;
  const bf16* X2 = ws + (s ? OFF_BUFU : OFF_BUFD) + (size_t)b * CHW;
  const bf16* Wg = ws + (s ? OFF_W2A : OFF_W1A);
  bf16* Mo = ws + (s ? OFF_QDU : OFF_QUD) + (size_t)b * CHW;  // mid aliases q

  const f32x4 zero4 = {0.f, 0.f, 0.f, 0.f};
  f32x4 acc[2][2][4];
#pragma unroll
  for (int r = 0; r < 2; ++r)
#pragma unroll
    for (int xt = 0; xt < 2; ++xt)
#pragma unroll
      for (int ot = 0; ot < 4; ++ot) acc[r][xt][ot] = zero4;

  for (int t = 0; t < 2; ++t) {
    __syncthreads();                       // LDS reuse guard (no-op 1st iter)
    const bf16* Xt = t ? X2 : X1;
    STAGE_SLAB(Xt);
    __syncthreads();
    bf16x8 bw[2][4], af[2][2][2];
    LOADW1(0, 0);
    LOADA(0, 0);
#pragma unroll
    for (int g = 0; g < 18; ++g) {
      const int cur = g & 1, nxt = cur ^ 1;
      if (g < 17) {
        LOADW1(g + 1, nxt);
        LOADA(g + 1, nxt);
      }
#pragma unroll
      for (int r = 0; r < 2; ++r)
#pragma unroll
        for (int xt = 0; xt < 2; ++xt)
#pragma unroll
          for (int ot = 0; ot < 4; ++ot)
            acc[r][xt][ot] = MFMA(af[cur][r][xt], bw[cur][ot], acc[r][xt][ot]);
    }
  }
  // ReLU + per-wave transpose epilogue -> mid [b,h,w,c] bf16
#pragma unroll
  for (int r = 0; r < 2; ++r)
#pragma unroll
    for (int xt = 0; xt < 2; ++xt) {
#pragma unroll
      for (int ot = 0; ot < 4; ++ot)
#pragma unroll
        for (int rr = 0; rr < 4; ++rr)
          stg[wv][q4 * 4 + rr][ot * 16 + l15] = (bf16)fmaxf(acc[r][xt][ot][rr], 0.f);
      __builtin_amdgcn_s_waitcnt(0);       // lgkm drain before re-read
      bf16x8 w0, w1;
      const int cc = q4 * 16;
#pragma unroll
      for (int j = 0; j < 8; ++j) {
        w0[j] = stg[wv][l15][cc + j];
        w1[j] = stg[wv][l15][cc + 8 + j];
      }
      const int y = y0 + wv * 2 + r;
      bf16* p = Mo + ((size_t)y * 320 + x0 + xt * 16 + l15) * 64 + cc;
      *(bf16x8*)p = w0;
      *(bf16x8*)(p + 8) = w1;
    }
}

// ---------------------------------------------------------------------------
// kconv2 v4: same skeleton, single 64-ch tensor (K=576), fp32 NCHW output
// straight from C-layout.  grid (10, 40, 4).
__global__ __launch_bounds__(256, 3) void kconv2(const bf16* __restrict__ ws,
                                                 float* __restrict__ out) {
  __shared__ __attribute__((aligned(16))) bf16 xs[10 * 8 * 34 * 8];  // 43520 B
  const int s = blockIdx.z >> 1, b = blockIdx.z & 1;
  const int x0 = blockIdx.x * 32;
  const int y0 = blockIdx.y * 8;
  const int tid = threadIdx.x;
  const int lane = tid & 63, wv = tid >> 6;
  const int l15 = lane & 15, q4 = lane >> 4;

  const bf16* X  = ws + (s ? OFF_QDU : OFF_QUD) + (size_t)b * CHW;  // mid
  const bf16* Wg = ws + (s ? OFF_W2B : OFF_W1B);
  float* O = out + (size_t)s * NE + (size_t)b * CHW;

  const f32x4 zero4 = {0.f, 0.f, 0.f, 0.f};
  f32x4 acc[2][2][4];
#pragma unroll
  for (int r = 0; r < 2; ++r)
#pragma unroll
    for (int xt = 0; xt < 2; ++xt)
#pragma unroll
      for (int ot = 0; ot < 4; ++ot) acc[r][xt][ot] = zero4;

  STAGE_SLAB(X);
  __syncthreads();
  {
    bf16x8 bw[2][4], af[2][2][2];
    LOADW2(0, 0);
    LOADA(0, 0);
#pragma unroll
    for (int g = 0; g < 18; ++g) {
      const int cur = g & 1, nxt = cur ^ 1;
      if (g < 17) {
        LOADW2(g + 1, nxt);
        LOADA(g + 1, nxt);
      }
#pragma unroll
      for (int r = 0; r < 2; ++r)
#pragma unroll
        for (int xt = 0; xt < 2; ++xt)
#pragma unroll
          for (int ot = 0; ot < 4; ++ot)
            acc[r][xt][ot] = MFMA(af[cur][r][xt], bw[cur][ot], acc[r][xt][ot]);
    }
  }
  // fp32 NCHW store: row=(lane>>4)*4+reg (px), col=lane&15 (out ch)
#pragma unroll
  for (int r = 0; r < 2; ++r)
#pragma unroll
    for (int xt = 0; xt < 2; ++xt)
#pragma unroll
      for (int ot = 0; ot < 4; ++ot) {
        const int o = ot * 16 + l15;
        const int y = y0 + wv * 2 + r;
        float* p = O + (size_t)o * HWc + (size_t)y * 320 + x0 + xt * 16 + q4 * 4;
        *(f32x4*)p = acc[r][xt][ot];
      }
}

// ---------------------------------------------------------------------------
extern "C" void kernel_launch(void* const* d_in, const int* in_sizes, int n_in,
                              void* d_out, int out_size, void* d_ws, size_t ws_size,
                              hipStream_t stream) {
  const float* u   = (const float*)d_in[0];
  const float* d   = (const float*)d_in[1];
  const float* Wu1 = (const float*)d_in[2];
  const float* Wu2 = (const float*)d_in[3];
  const float* Wd1 = (const float*)d_in[4];
  const float* Wd2 = (const float*)d_in[5];
  const float* W1a = (const float*)d_in[6];
  const float* W1b = (const float*)d_in[7];
  const float* W2a = (const float*)d_in[8];
  const float* W2b = (const float*)d_in[9];
  bf16* ws = (bf16*)d_ws;
  float* out = (float*)d_out;

  kpack<<<dim3((9 * 64 * 128 + 255) / 256), 256, 0, stream>>>(
      Wu1, Wu2, Wd1, Wd2, W1a, W1b, W2a, W2b, ws);
  kproj<<<dim3(5, 640, 2), 256, 0, stream>>>(u, d, ws);
  kattn<<<dim3(6400), 256, 0, stream>>>(ws);
  kconv1<<<dim3(10, 40, 4), 256, 0, stream>>>(ws);
  kconv2<<<dim3(10, 40, 4), 256, 0, stream>>>(ws, out);
}

// Round 12
// 658.558 us; speedup vs baseline: 1.0545x; 1.0545x over previous
//
#include <hip/hip_runtime.h>
#include <stdint.h>

// ---------------------------------------------------------------------------
// IAM_47794396069954: dual-stream axial (row-wise) cross attention + double
// 3x3 conv heads, b=2, c=64, h=w=320.  All heavy math on bf16 MFMA
// (mfma_f32_16x16x32_bf16), fp32 accumulate.  5 kernels:
//   kpack  : weights -> bf16, conv weights repacked [tap][o][c]
//   kproj  : u/d -> bf16 NCHW copy + [b,h,w,c] transpose + 4x 1x1 proj (MFMA)
//   kattn  : per-(b,h,dir,qtile) row attention, K staged in LDS
//            v3c: R6-measured structure (sibling-coherent map + XOR swizzle
//            + separate pch, 50176B LDS) + Q-fragment hoist + deferred
//            P-normalization (inv applied in epilogue, not at P-write).
//   kconv1 : LDS-staged implicit-GEMM 3x3 (concat 128ch) + ReLU -> mid bf16
//            v4: reg-staged loads + tap-group SW pipeline  [measured R5/R6]
//   kconv2 : LDS-staged implicit-GEMM 3x3 (64ch) -> fp32 NCHW, same pipeline
// NOTE (R2 lesson): __launch_bounds__(256,4) caused accumulator spills.
// NOTE (R5 lesson): t5 siblings must be CONCURRENT and co-XCD for L2 reuse.
// NOTE (R7 lesson): 16-segment channel-plane gathers feeding MFMA are the
// expensive pattern; LDS staging is an MLP converter, not just a cache.
// NOTE (R9 lesson): holding V in VGPRs across QK tanked occupancy.
// NOTE (R10/R11): the global_load_lds V-staging line burned 3 rounds on
// container failures with no data; abandoned in favor of the measured-best
// R6 structure + two DMA-independent micro-opts.
// MFMA 16x16x32 layouts:
//   A[m][k]: m=lane&15, k=(lane>>4)*8+j ;  B[k][n]: n=lane&15, k=(lane>>4)*8+j
//   C/D    : col=lane&15, row=(lane>>4)*4+reg
// ---------------------------------------------------------------------------

typedef __bf16 bf16;
typedef __bf16 bf16x8 __attribute__((ext_vector_type(8)));
typedef float  f32x4  __attribute__((ext_vector_type(4)));

#define MFMA(a, b, c) __builtin_amdgcn_mfma_f32_16x16x32_bf16((a), (b), (c), 0, 0, 0)

static constexpr int    HWc  = 320 * 320;      // 102400
static constexpr int    CHW  = 64 * HWc;       // 6553600
static constexpr size_t NE   = 2ull * CHW;     // 13107200 elements per tensor

// workspace layout (bf16 elements)
static constexpr size_t OFF_UBF  = 0;          // u bf16 NCHW (attn V)
static constexpr size_t OFF_DBF  = NE;         // d bf16 NCHW (attn V)
static constexpr size_t OFF_UT   = 2 * NE;     // u  [b,h,w,c]
static constexpr size_t OFF_DT   = 3 * NE;     // d  [b,h,w,c]
static constexpr size_t OFF_QUD  = 4 * NE;     // u1 [b,h,w,c]; later mid_u
static constexpr size_t OFF_KUD  = 5 * NE;     // d2
static constexpr size_t OFF_QDU  = 6 * NE;     // d1 ; later mid_d
static constexpr size_t OFF_KDU  = 7 * NE;     // u2
static constexpr size_t OFF_BUFD = 8 * NE;     // buffer_d [b,h,w,c]
static constexpr size_t OFF_BUFU = 9 * NE;     // buffer_u [b,h,w,c]
static constexpr size_t OFF_W1A  = 10 * NE;            // [9][64][128]
static constexpr size_t OFF_W2A  = OFF_W1A + 9*64*128;
static constexpr size_t OFF_W1B  = OFF_W2A + 9*64*128; // [9][64][64]
static constexpr size_t OFF_W2B  = OFF_W1B + 9*64*64;
static constexpr size_t OFF_WU1  = OFF_W2B + 9*64*64;  // [64][64]
static constexpr size_t OFF_WU2  = OFF_WU1 + 4096;
static constexpr size_t OFF_WD1  = OFF_WU2 + 4096;
static constexpr size_t OFF_WD2  = OFF_WD1 + 4096;

// ---------------------------------------------------------------------------
__global__ __launch_bounds__(256) void kpack(
    const float* __restrict__ Wu1, const float* __restrict__ Wu2,
    const float* __restrict__ Wd1, const float* __restrict__ Wd2,
    const float* __restrict__ W1a, const float* __restrict__ W1b,
    const float* __restrict__ W2a, const float* __restrict__ W2b,
    bf16* __restrict__ ws) {
  const int t = blockIdx.x * 256 + threadIdx.x;
  if (t < 9 * 64 * 128) {                 // [tap][o][c] <- W[o][c][ky][kx]
    const int c = t & 127, o = (t >> 7) & 63, tap = t >> 13;
    const int src = (o * 128 + c) * 9 + tap;
    ws[OFF_W1A + t] = (bf16)W1a[src];
    ws[OFF_W2A + t] = (bf16)W2a[src];
  }
  if (t < 9 * 64 * 64) {
    const int c = t & 63, o = (t >> 6) & 63, tap = t >> 12;
    const int src = (o * 64 + c) * 9 + tap;
    ws[OFF_W1B + t] = (bf16)W1b[src];
    ws[OFF_W2B + t] = (bf16)W2b[src];
  }
  if (t < 4096) {
    ws[OFF_WU1 + t] = (bf16)Wu1[t];
    ws[OFF_WU2 + t] = (bf16)Wu2[t];
    ws[OFF_WD1 + t] = (bf16)Wd1[t];
    ws[OFF_WD2 + t] = (bf16)Wd2[t];
  }
}

// ---------------------------------------------------------------------------
// grid (5, 640, 2): x = 64-px tile, y = b*320+h, z = stream (0=u,1=d)
__global__ __launch_bounds__(256) void kproj(const float* __restrict__ u,
                                             const float* __restrict__ d,
                                             bf16* __restrict__ ws) {
  __shared__ float ut[64][68];        // [x][c]
  __shared__ float stg[4][16][68];    // per-wave transpose stage
  const int s   = blockIdx.z;
  const int by  = blockIdx.y;               // b*320 + y
  const int b   = by / 320;
  const int y   = by % 320;
  const int x0  = blockIdx.x * 64;
  const int tid = threadIdx.x;
  const int lane = tid & 63, wv = tid >> 6;
  const int l15 = lane & 15, q4 = lane >> 4;

  const float* src = s ? d : u;
  const bf16* Wq = ws + (s ? OFF_WD1 : OFF_WU1);   // u1 / d1
  const bf16* Wk = ws + (s ? OFF_WD2 : OFF_WU2);   // u2 / d2
  bf16* xbf = ws + (s ? OFF_DBF : OFF_UBF);
  bf16* xt  = ws + (s ? OFF_DT  : OFF_UT);
  bf16* qo  = ws + (s ? OFF_QDU : OFF_QUD);        // u1->q_ud, d1->q_du
  bf16* ko  = ws + (s ? OFF_KUD : OFF_KDU);        // u2->k_du, d2->k_ud

  // phase 1: coalesced load, bf16 NCHW copy, LDS transpose stage
  {
    const int xl = lane;
    const int cb = wv * 16;
#pragma unroll
    for (int i = 0; i < 16; ++i) {
      const int c = cb + i;
      const size_t g = (size_t)(b * 64 + c) * HWc + (size_t)y * 320 + x0 + xl;
      const float v = src[g];
      xbf[g] = (bf16)v;
      ut[xl][c] = v;
    }
  }
  __syncthreads();

  // phase 1b: [b,h,w,c] transpose store
  {
    const int xl = tid >> 2;
    const int cc = (tid & 3) * 16;
    bf16x8 v0, v1;
#pragma unroll
    for (int j = 0; j < 8; ++j) {
      v0[j] = (bf16)ut[xl][cc + j];
      v1[j] = (bf16)ut[xl][cc + 8 + j];
    }
    bf16* p = xt + ((size_t)by * 320 + x0 + xl) * 64 + cc;
    *(bf16x8*)p = v0;
    *(bf16x8*)(p + 8) = v1;
  }

  // phase 2: 1x1 projections.  wave wv handles x-subtile wv*16..+15
  bf16x8 a[2];
#pragma unroll
  for (int ks = 0; ks < 2; ++ks) {
    const int xl = wv * 16 + l15;
    const int c0 = ks * 32 + q4 * 8;
#pragma unroll
    for (int j = 0; j < 8; ++j) a[ks][j] = (bf16)ut[xl][c0 + j];
  }
  const f32x4 zero4 = {0.f, 0.f, 0.f, 0.f};
  f32x4 acc[8];
#pragma unroll
  for (int i = 0; i < 8; ++i) acc[i] = zero4;
#pragma unroll
  for (int ks = 0; ks < 2; ++ks) {
#pragma unroll
    for (int ot = 0; ot < 8; ++ot) {
      const bf16* Wm = (ot < 4) ? Wq : Wk;
      const int o = (ot & 3) * 16 + l15;
      const bf16x8 bw = *(const bf16x8*)(Wm + o * 64 + ks * 32 + q4 * 8);
      acc[ot] = MFMA(a[ks], bw, acc[ot]);
    }
  }
  // epilogue: two passes (q then k), per-wave LDS transpose, 32B stores
#pragma unroll
  for (int pass = 0; pass < 2; ++pass) {
    bf16* dst = pass ? ko : qo;
#pragma unroll
    for (int ot = 0; ot < 4; ++ot)
#pragma unroll
      for (int r = 0; r < 4; ++r)
        stg[wv][q4 * 4 + r][ot * 16 + l15] = acc[pass * 4 + ot][r];
    bf16x8 v0, v1;
    const int cc = q4 * 16;
#pragma unroll
    for (int j = 0; j < 8; ++j) {
      v0[j] = (bf16)stg[wv][l15][cc + j];
      v1[j] = (bf16)stg[wv][l15][cc + 8 + j];
    }
    bf16* p = dst + ((size_t)by * 320 + x0 + wv * 16 + l15) * 64 + cc;
    *(bf16x8*)p = v0;
    *(bf16x8*)(p + 8) = v1;
  }
}

// ---------------------------------------------------------------------------
// kattn v3c: 1-D grid 6400.  g -> chunk=g/40, t5=(g%40)>>3, bhdir=chunk*8+
// (g%40&7).  The 5 t5-siblings of a (bh,dir) sit at ids {base,base+8,..,
// base+32}: same XCD (i%8 round-robin) AND same dispatch window -> K/V L2-hot
// (verified R6: FETCH 281->77MB).  ksh layout [t][s][r] with XOR swizzle
// (verified R6: conflicts 15.6M->1.2M).  Changes vs measured R6 source:
// Q fragments hoisted above staging; P written unnormalized with inv folded
// into the 16-value epilogue (saves 64 VALU mul on the serial chain).
__global__ __launch_bounds__(256) void kattn(bf16* __restrict__ ws) {
  __shared__ __attribute__((aligned(16))) bf16 ksh[20480];          // 40960 B
  __shared__ __attribute__((aligned(16))) bf16 pch[4][16][72];      //  9216 B
  const int g     = blockIdx.x;
  const int chunk = g / 40;
  const int within = g % 40;
  const int t5    = within >> 3;
  const int bhdir = chunk * 8 + (within & 7);
  const int bh    = bhdir % 640;
  const int dir   = bhdir / 640;
  const int tid = threadIdx.x;
  const int lane = tid & 63, wv = tid >> 6;
  const int l15 = lane & 15, q4 = lane >> 4;

  const bf16* Q = ws + (dir ? OFF_QDU : OFF_QUD) + (size_t)bh * 320 * 64;
  const bf16* K = ws + (dir ? OFF_KDU : OFF_KUD) + (size_t)bh * 320 * 64;
  const bf16* V = ws + (dir ? OFF_UBF : OFF_DBF) + (size_t)(bh / 320) * CHW
                + (size_t)(bh % 320) * 320;
  bf16* O = ws + (dir ? OFF_BUFU : OFF_BUFD) + (size_t)bh * 320 * 64;

  // Q fragments first: their load latency overlaps the K staging below
  const int wq0 = (t5 * 4 + wv) * 16;
  const bf16x8 a0 = *(const bf16x8*)(Q + (size_t)(wq0 + l15) * 64 + q4 * 8);
  const bf16x8 a1 = *(const bf16x8*)(Q + (size_t)(wq0 + l15) * 64 + 32 + q4 * 8);

  // stage K -> LDS: 2560 chunks of 16B, 10 per thread, coalesced source
  for (int i = tid; i < 2560; i += 256) {
    const int px = i >> 3, s = i & 7;          // key px, c-chunk
    const int t = px >> 4, r = px & 15;
    const int off = t * 1024 + s * 128 + (((r & 7) ^ s) << 3) + ((r & 8) << 3);
    *(bf16x8*)(ksh + off) = *(const bf16x8*)(K + (size_t)px * 64 + s * 8);
  }
  __syncthreads();

  const f32x4 zero4 = {0.f, 0.f, 0.f, 0.f};
  // swizzled read offsets (constant per lane across kt)
  const int rb0 = q4 * 128 + (((l15 & 7) ^ q4) << 3) + ((l15 & 8) << 3);
  const int rb1 = (q4 + 4) * 128 + (((l15 & 7) ^ (q4 + 4)) << 3) + ((l15 & 8) << 3);
  f32x4 sacc[20];
#pragma unroll
  for (int kt = 0; kt < 20; ++kt) sacc[kt] = zero4;
#pragma unroll
  for (int kt = 0; kt < 20; ++kt) {
    const bf16x8 b0 = *(const bf16x8*)(ksh + kt * 1024 + rb0);
    const bf16x8 b1 = *(const bf16x8*)(ksh + kt * 1024 + rb1);
    sacc[kt] = MFMA(a0, b0, sacc[kt]);
    sacc[kt] = MFMA(a1, b1, sacc[kt]);
  }
  // exact softmax over the 320-wide row; row wq = q4*4+r lives in this quad
  float mx[4] = {-3.0e38f, -3.0e38f, -3.0e38f, -3.0e38f};
#pragma unroll
  for (int kt = 0; kt < 20; ++kt)
#pragma unroll
    for (int r = 0; r < 4; ++r) mx[r] = fmaxf(mx[r], sacc[kt][r]);
#pragma unroll
  for (int off = 1; off < 16; off <<= 1)
#pragma unroll
    for (int r = 0; r < 4; ++r) mx[r] = fmaxf(mx[r], __shfl_xor(mx[r], off));
  float sm[4] = {0.f, 0.f, 0.f, 0.f};
#pragma unroll
  for (int kt = 0; kt < 20; ++kt)
#pragma unroll
    for (int r = 0; r < 4; ++r) {
      const float e = __expf(sacc[kt][r] - mx[r]);
      sacc[kt][r] = e;
      sm[r] += e;
    }
#pragma unroll
  for (int off = 1; off < 16; off <<= 1)
#pragma unroll
    for (int r = 0; r < 4; ++r) sm[r] += __shfl_xor(sm[r], off);
  float inv[4];
#pragma unroll
  for (int r = 0; r < 4; ++r) inv[r] = 1.f / sm[r];

  // PV: chunks of 64 v; P (UNNORMALIZED, e<=1) C-layout -> LDS -> A-layout
  f32x4 oac[4];
#pragma unroll
  for (int ct = 0; ct < 4; ++ct) oac[ct] = zero4;
#pragma unroll
  for (int ch = 0; ch < 5; ++ch) {
#pragma unroll
    for (int j = 0; j < 4; ++j) {
      const int kt = ch * 4 + j;
#pragma unroll
      for (int r = 0; r < 4; ++r)
        pch[wv][q4 * 4 + r][j * 16 + l15] = (bf16)sacc[kt][r];
    }
    const bf16x8 p0 = *(const bf16x8*)&pch[wv][l15][q4 * 8];
    const bf16x8 p1 = *(const bf16x8*)&pch[wv][l15][32 + q4 * 8];
#pragma unroll
    for (int ct = 0; ct < 4; ++ct) {
      const bf16* vp = V + (size_t)(ct * 16 + l15) * HWc + ch * 64 + q4 * 8;
      const bf16x8 v0 = *(const bf16x8*)vp;
      const bf16x8 v1 = *(const bf16x8*)(vp + 32);
      oac[ct] = MFMA(p0, v0, oac[ct]);
      oac[ct] = MFMA(p1, v1, oac[ct]);
    }
  }
  // epilogue: normalize by inv[r]; O[wq][c] -> [b,h,w,c] via pch transpose
#pragma unroll
  for (int ct = 0; ct < 4; ++ct)
#pragma unroll
    for (int r = 0; r < 4; ++r)
      pch[wv][q4 * 4 + r][ct * 16 + l15] = (bf16)(oac[ct][r] * inv[r]);
  __builtin_amdgcn_s_waitcnt(0);           // lgkm drain before re-read
  bf16x8 w0, w1;
  const int cc = q4 * 16;
#pragma unroll
  for (int j = 0; j < 8; ++j) {
    w0[j] = pch[wv][l15][cc + j];
    w1[j] = pch[wv][l15][cc + 8 + j];
  }
  bf16* p = O + (size_t)(wq0 + l15) * 64 + cc;
  *(bf16x8*)p = w0;
  *(bf16x8*)(p + 8) = w1;
}

// ---------------------------------------------------------------------------
// reg-staged slab fill: issue independent global loads first, then LDS writes.
// 2720 16B-chunks = 10 full rounds of 256 threads + 160-thread tail.
#define STAGE_SLAB(XT)                                                        \
  do {                                                                        \
    bf16x8 vr[11];                                                            \
    _Pragma("unroll") for (int it = 0; it < 10; ++it) {                       \
      const int i = tid + it * 256;                                           \
      const int row = i / 272, rem = i % 272;                                 \
      const int px = rem >> 3, chunk = rem & 7;                               \
      const int yy = y0 - 1 + row, xx = x0 - 1 + px;                          \
      bf16x8 v;                                                               \
      _Pragma("unroll") for (int j = 0; j < 8; ++j) v[j] = (bf16)0.f;         \
      if ((unsigned)yy < 320u && (unsigned)xx < 320u)                         \
        v = *(const bf16x8*)((XT) + ((size_t)yy * 320 + xx) * 64 + chunk * 8);\
      vr[it] = v;                                                             \
    }                                                                         \
    if (tid < 160) {                                                          \
      const int i = tid + 2560;                                               \
      const int row = i / 272, rem = i % 272;                                 \
      const int px = rem >> 3, chunk = rem & 7;                               \
      const int yy = y0 - 1 + row, xx = x0 - 1 + px;                          \
      bf16x8 v;                                                               \
      _Pragma("unroll") for (int j = 0; j < 8; ++j) v[j] = (bf16)0.f;         \
      if ((unsigned)yy < 320u && (unsigned)xx < 320u)                         \
        v = *(const bf16x8*)((XT) + ((size_t)yy * 320 + xx) * 64 + chunk * 8);\
      vr[10] = v;                                                             \
    }                                                                         \
    _Pragma("unroll") for (int it = 0; it < 10; ++it) {                       \
      const int i = tid + it * 256;                                           \
      const int row = i / 272, rem = i % 272;                                 \
      const int px = rem >> 3, chunk = rem & 7;                               \
      *(bf16x8*)(xs + (((row * 8 + chunk) * 34 + px) * 8)) = vr[it];          \
    }                                                                         \
    if (tid < 160) {                                                          \
      const int i = tid + 2560;                                               \
      const int row = i / 272, rem = i % 272;                                 \
      const int px = rem >> 3, chunk = rem & 7;                               \
      *(bf16x8*)(xs + (((row * 8 + chunk) * 34 + px) * 8)) = vr[10];          \
    }                                                                         \
  } while (0)

// group g = tap*2 + ks; weight fragments (4x16B, L2) for kconv1 (cin stride 128)
#define LOADW1(g, slot)                                                       \
  do {                                                                        \
    const bf16* wp_ = Wg + (size_t)((g) >> 1) * 8192 + (size_t)l15 * 128      \
                      + t * 64 + ((g) & 1) * 32 + q4 * 8;                     \
    bw[slot][0] = *(const bf16x8*)(wp_);                                      \
    bw[slot][1] = *(const bf16x8*)(wp_ + 2048);                               \
    bw[slot][2] = *(const bf16x8*)(wp_ + 4096);                               \
    bw[slot][3] = *(const bf16x8*)(wp_ + 6144);                               \
  } while (0)

// weight fragments for kconv2 (cin stride 64)
#define LOADW2(g, slot)                                                       \
  do {                                                                        \
    const bf16* wp_ = Wg + (size_t)((g) >> 1) * 4096 + (size_t)l15 * 64       \
                      + ((g) & 1) * 32 + q4 * 8;                              \
    bw[slot][0] = *(const bf16x8*)(wp_);                                      \
    bw[slot][1] = *(const bf16x8*)(wp_ + 1024);                               \
    bw[slot][2] = *(const bf16x8*)(wp_ + 2048);                               \
    bw[slot][3] = *(const bf16x8*)(wp_ + 3072);                               \
  } while (0)

// A fragments from LDS slab (4x ds_read_b128); [r][xt]
#define LOADA(g, slot)                                                        \
  do {                                                                        \
    const int ky_ = (g) / 6, kx_ = ((g) >> 1) % 3, ks_ = (g) & 1;             \
    const bf16* ap_ = xs + (((wv * 2 + ky_) * 8 + ks_ * 4 + q4) * 34          \
                            + l15 + kx_) * 8;                                 \
    af[slot][0][0] = *(const bf16x8*)(ap_);                                   \
    af[slot][0][1] = *(const bf16x8*)(ap_ + 128);                             \
    af[slot][1][0] = *(const bf16x8*)(ap_ + 2176);                            \
    af[slot][1][1] = *(const bf16x8*)(ap_ + 2304);                            \
  } while (0)

// ---------------------------------------------------------------------------
// kconv1 v4: grid (10, 40, 4): 32-px x-tile, 8-row y-tile, z = s*2+b.
// 2 phases (concat halves), slab [10 rows][8 ch-chunks][34 px] (43.5 KB).
// Inner loop: 18 tap-groups, software-pipelined (prefetch g+1 while MFMA g).
__global__ __launch_bounds__(256, 3) void kconv1(bf16* __restrict__ ws) {
  __shared__ __attribute__((aligned(16))) bf16 xs[10 * 8 * 34 * 8];  // 43520 B
  __shared__ __attribute__((aligned(16))) bf16 stg[4][16][72];       //  9216 B
  const int s = blockIdx.z >> 1, b = blockIdx.z & 1;
  const int x0 = blockIdx.x * 32;
  const int y0 = blockIdx.y * 8;
  const int tid = threadIdx.x;
  const int lane = tid & 63, wv = tid >> 6;
  const int l15 = lane & 15, q4 = lane >> 4;

  const bf16* X1 = ws + (s ? OFF_DT : OFF_UT) + (size_t)b * CHW;
  const bf16* X2 = ws + (s ? OFF_BUFU : OFF_BUFD) + (size_t)b * CHW;
  const bf16* Wg = ws + (s ? OFF_W2A : OFF_W1A);
  bf16* Mo = ws + (s ? OFF_QDU : OFF_QUD) + (size_t)b * CHW;  // mid aliases q

  const f32x4 zero4 = {0.f, 0.f, 0.f, 0.f};
  f32x4 acc[2][2][4];
#pragma unroll
  for (int r = 0; r < 2; ++r)
#pragma unroll
    for (int xt = 0; xt < 2; ++xt)
#pragma unroll
      for (int ot = 0; ot < 4; ++ot) acc[r][xt][ot] = zero4;

  for (int t = 0; t < 2; ++t) {
    __syncthreads();                       // LDS reuse guard (no-op 1st iter)
    const bf16* Xt = t ? X2 : X1;
    STAGE_SLAB(Xt);
    __syncthreads();
    bf16x8 bw[2][4], af[2][2][2];
    LOADW1(0, 0);
    LOADA(0, 0);
#pragma unroll
    for (int g = 0; g < 18; ++g) {
      const int cur = g & 1, nxt = cur ^ 1;
      if (g < 17) {
        LOADW1(g + 1, nxt);
        LOADA(g + 1, nxt);
      }
#pragma unroll
      for (int r = 0; r < 2; ++r)
#pragma unroll
        for (int xt = 0; xt < 2; ++xt)
#pragma unroll
          for (int ot = 0; ot < 4; ++ot)
            acc[r][xt][ot] = MFMA(af[cur][r][xt], bw[cur][ot], acc[r][xt][ot]);
    }
  }
  // ReLU + per-wave transpose epilogue -> mid [b,h,w,c] bf16
#pragma unroll
  for (int r = 0; r < 2; ++r)
#pragma unroll
    for (int xt = 0; xt < 2; ++xt) {
#pragma unroll
      for (int ot = 0; ot < 4; ++ot)
#pragma unroll
        for (int rr = 0; rr < 4; ++rr)
          stg[wv][q4 * 4 + rr][ot * 16 + l15] = (bf16)fmaxf(acc[r][xt][ot][rr], 0.f);
      __builtin_amdgcn_s_waitcnt(0);       // lgkm drain before re-read
      bf16x8 w0, w1;
      const int cc = q4 * 16;
#pragma unroll
      for (int j = 0; j < 8; ++j) {
        w0[j] = stg[wv][l15][cc + j];
        w1[j] = stg[wv][l15][cc + 8 + j];
      }
      const int y = y0 + wv * 2 + r;
      bf16* p = Mo + ((size_t)y * 320 + x0 + xt * 16 + l15) * 64 + cc;
      *(bf16x8*)p = w0;
      *(bf16x8*)(p + 8) = w1;
    }
}

// ---------------------------------------------------------------------------
// kconv2 v4: same skeleton, single 64-ch tensor (K=576), fp32 NCHW output
// straight from C-layout.  grid (10, 40, 4).
__global__ __launch_bounds__(256, 3) void kconv2(const bf16* __restrict__ ws,
                                                 float* __restrict__ out) {
  __shared__ __attribute__((aligned(16))) bf16 xs[10 * 8 * 34 * 8];  // 43520 B
  const int s = blockIdx.z >> 1, b = blockIdx.z & 1;
  const int x0 = blockIdx.x * 32;
  const int y0 = blockIdx.y * 8;
  const int tid = threadIdx.x;
  const int lane = tid & 63, wv = tid >> 6;
  const int l15 = lane & 15, q4 = lane >> 4;

  const bf16* X  = ws + (s ? OFF_QDU : OFF_QUD) + (size_t)b * CHW;  // mid
  const bf16* Wg = ws + (s ? OFF_W2B : OFF_W1B);
  float* O = out + (size_t)s * NE + (size_t)b * CHW;

  const f32x4 zero4 = {0.f, 0.f, 0.f, 0.f};
  f32x4 acc[2][2][4];
#pragma unroll
  for (int r = 0; r < 2; ++r)
#pragma unroll
    for (int xt = 0; xt < 2; ++xt)
#pragma unroll
      for (int ot = 0; ot < 4; ++ot) acc[r][xt][ot] = zero4;

  STAGE_SLAB(X);
  __syncthreads();
  {
    bf16x8 bw[2][4], af[2][2][2];
    LOADW2(0, 0);
    LOADA(0, 0);
#pragma unroll
    for (int g = 0; g < 18; ++g) {
      const int cur = g & 1, nxt = cur ^ 1;
      if (g < 17) {
        LOADW2(g + 1, nxt);
        LOADA(g + 1, nxt);
      }
#pragma unroll
      for (int r = 0; r < 2; ++r)
#pragma unroll
        for (int xt = 0; xt < 2; ++xt)
#pragma unroll
          for (int ot = 0; ot < 4; ++ot)
            acc[r][xt][ot] = MFMA(af[cur][r][xt], bw[cur][ot], acc[r][xt][ot]);
    }
  }
  // fp32 NCHW store: row=(lane>>4)*4+reg (px), col=lane&15 (out ch)
#pragma unroll
  for (int r = 0; r < 2; ++r)
#pragma unroll
    for (int xt = 0; xt < 2; ++xt)
#pragma unroll
      for (int ot = 0; ot < 4; ++ot) {
        const int o = ot * 16 + l15;
        const int y = y0 + wv * 2 + r;
        float* p = O + (size_t)o * HWc + (size_t)y * 320 + x0 + xt * 16 + q4 * 4;
        *(f32x4*)p = acc[r][xt][ot];
      }
}

// ---------------------------------------------------------------------------
extern "C" void kernel_launch(void* const* d_in, const int* in_sizes, int n_in,
                              void* d_out, int out_size, void* d_ws, size_t ws_size,
                              hipStream_t stream) {
  const float* u   = (const float*)d_in[0];
  const float* d   = (const float*)d_in[1];
  const float* Wu1 = (const float*)d_in[2];
  const float* Wu2 = (const float*)d_in[3];
  const float* Wd1 = (const float*)d_in[4];
  const float* Wd2 = (const float*)d_in[5];
  const float* W1a = (const float*)d_in[6];
  const float* W1b = (const float*)d_in[7];
  const float* W2a = (const float*)d_in[8];
  const float* W2b = (const float*)d_in[9];
  bf16* ws = (bf16*)d_ws;
  float* out = (float*)d_out;

  kpack<<<dim3((9 * 64 * 128 + 255) / 256), 256, 0, stream>>>(
      Wu1, Wu2, Wd1, Wd2, W1a, W1b, W2a, W2b, ws);
  kproj<<<dim3(5, 640, 2), 256, 0, stream>>>(u, d, ws);
  kattn<<<dim3(6400), 256, 0, stream>>>(ws);
  kconv1<<<dim3(10, 40, 4), 256, 0, stream>>>(ws);
  kconv2<<<dim3(10, 40, 4), 256, 0, stream>>>(ws, out);
}